// Round 1
// baseline (1640.546 us; speedup 1.0000x reference)
//
#include <hip/hip_runtime.h>

// Problem constants
#define S_LEN 2048
#define EMB   2048
#define NQH   32
#define NKVH  8
#define HDIM  64
#define KVD   512
#define BATCH 2

typedef __bf16 bf16_t;
typedef __bf16 bf16x8 __attribute__((ext_vector_type(8)));
typedef __bf16 bf16x4 __attribute__((ext_vector_type(4)));
typedef float  f32x4  __attribute__((ext_vector_type(4)));

#define MFMA16(a, b, c) __builtin_amdgcn_mfma_f32_16x16x32_bf16(a, b, c, 0, 0, 0)

__device__ __forceinline__ void async_copy16(const void* gsrc, void* ldst) {
  __builtin_amdgcn_global_load_lds(
      (__attribute__((address_space(1))) void*)gsrc,
      (__attribute__((address_space(3))) void*)ldst, 16, 0, 0);
}

// ---------------- elementwise f32 -> bf16 ----------------
__global__ __launch_bounds__(256) void cvt_f32_bf16(const float* __restrict__ in,
                                                    bf16_t* __restrict__ out, int n) {
  int i = (blockIdx.x * 256 + threadIdx.x) * 4;
  if (i >= n) return;
  float4 v = *(const float4*)(in + i);
  bf16x4 o = {(bf16_t)v.x, (bf16_t)v.y, (bf16_t)v.z, (bf16_t)v.w};
  *(bf16x4*)(out + i) = o;
}

// ---------------- out[c][r] = (bf16) in[r][c], R,C multiples of 32 ----------------
__global__ __launch_bounds__(256) void transpose_f32_bf16(const float* __restrict__ in,
                                                          bf16_t* __restrict__ out,
                                                          int R, int C) {
  __shared__ float tile[32][33];
  int c0 = blockIdx.x * 32, r0 = blockIdx.y * 32;
  int tx = threadIdx.x, ty = threadIdx.y;  // 32 x 8
#pragma unroll
  for (int i = 0; i < 32; i += 8)
    tile[ty + i][tx] = in[(size_t)(r0 + ty + i) * C + c0 + tx];
  __syncthreads();
#pragma unroll
  for (int i = 0; i < 32; i += 8)
    out[(size_t)(c0 + ty + i) * R + r0 + tx] = (bf16_t)tile[tx][ty + i];
}

// ---------------- per-z bf16 transpose: out[z][c][r] = in[z][r][c] ----------------
__global__ __launch_bounds__(256) void transpose_bf16(const bf16_t* __restrict__ in,
                                                      bf16_t* __restrict__ out,
                                                      int R, int C) {
  __shared__ bf16_t tile[32][33];
  size_t zoff = (size_t)blockIdx.z * R * C;
  int c0 = blockIdx.x * 32, r0 = blockIdx.y * 32;
  int tx = threadIdx.x, ty = threadIdx.y;
#pragma unroll
  for (int i = 0; i < 32; i += 8)
    tile[ty + i][tx] = in[zoff + (size_t)(r0 + ty + i) * C + c0 + tx];
  __syncthreads();
#pragma unroll
  for (int i = 0; i < 32; i += 8)
    out[zoff + (size_t)(c0 + ty + i) * R + r0 + tx] = tile[tx][ty + i];
}

// ---------------- GEMM: C = (A @ Bt^T + bias) * out_scale ----------------
// A: MxK bf16 row-major; Bt: NxK bf16 row-major (pre-transposed weights);
// bias: N fp32; C: MxN (OutT). M,N multiples of 128; K multiple of 32.
// m97 structure: 128x128 tile, BK=32, 4 waves (2x2 of 64x64), global_load_lds 16B.
template <typename OutT>
__global__ __launch_bounds__(256) void gemm_bt(const bf16_t* __restrict__ A,
                                               const bf16_t* __restrict__ Bt,
                                               const float* __restrict__ bias,
                                               OutT* __restrict__ C,
                                               int M, int N, int K, float out_scale) {
  __shared__ bf16_t ldsA[128 * 32];
  __shared__ bf16_t ldsB[128 * 32];
  const int tid = threadIdx.x;
  const int wave = tid >> 6, lane = tid & 63;
  const int wr = wave >> 1, wc = wave & 1;
  const int ll = lane & 15, quad = lane >> 4;
  const int n0 = blockIdx.x * 128, m0 = blockIdx.y * 128;
  const int srow = lane >> 2;  // 0..15
  const int scol = lane & 3;   // 0..3 (x8 bf16)

  f32x4 acc[4][4] = {};

  for (int k0 = 0; k0 < K; k0 += 32) {
    __syncthreads();
#pragma unroll
    for (int h = 0; h < 2; ++h) {
      int rbase = wave * 32 + h * 16;  // 16 rows per wave-load (1 KB)
      const bf16_t* ga = A  + (size_t)(m0 + rbase + srow) * K + k0 + scol * 8;
      const bf16_t* gb = Bt + (size_t)(n0 + rbase + srow) * K + k0 + scol * 8;
      async_copy16(ga, &ldsA[rbase * 32]);
      async_copy16(gb, &ldsB[rbase * 32]);
    }
    __syncthreads();
    bf16x8 af[4], bfr[4];
#pragma unroll
    for (int i = 0; i < 4; ++i) {
      af[i]  = *(const bf16x8*)&ldsA[(wr * 64 + i * 16 + ll) * 32 + quad * 8];
      bfr[i] = *(const bf16x8*)&ldsB[(wc * 64 + i * 16 + ll) * 32 + quad * 8];
    }
#pragma unroll
    for (int i = 0; i < 4; ++i)
#pragma unroll
      for (int j = 0; j < 4; ++j)
        acc[i][j] = MFMA16(af[i], bfr[j], acc[i][j]);
  }

  // epilogue: D element (row = quad*4+reg, col = lane&15)  [m89/m91-verified]
#pragma unroll
  for (int j = 0; j < 4; ++j) {
    int col = n0 + wc * 64 + j * 16 + ll;
    float bv = bias[col];
#pragma unroll
    for (int i = 0; i < 4; ++i) {
      int rowb = m0 + wr * 64 + i * 16 + quad * 4;
#pragma unroll
      for (int r = 0; r < 4; ++r) {
        float v = (acc[i][j][r] + bv) * out_scale;
        C[(size_t)(rowb + r) * N + col] = (OutT)v;
      }
    }
  }
}

// ---------------- GQA attention ----------------
// Qp: (B*S, EMB) bf16, already scaled by 1/sqrt(D).
// Kp: (B*S, KVD) bf16.  Vpt: (B, NKVH, HDIM, S) bf16 (V transposed).
// attn: (B, NQH, S, S) fp32 out.  Ob: (B*S, EMB) bf16 out.
// Block: 64 q-rows of one (b, hq). 4 waves, 16 q-rows each.
__global__ __launch_bounds__(256) void attn_kernel(const bf16_t* __restrict__ Qp,
                                                   const bf16_t* __restrict__ Kp,
                                                   const bf16_t* __restrict__ Vpt,
                                                   float* __restrict__ attn,
                                                   bf16_t* __restrict__ Ob) {
  const int qt = blockIdx.x;   // 0..31 (q tile of 64)
  const int hq = blockIdx.y;   // 0..31
  const int b  = blockIdx.z;   // 0..1
  const int hkv = hq >> 2;
  const int tid = threadIdx.x;
  const int wave = tid >> 6, lane = tid & 63;
  const int ll = lane & 15, quad = lane >> 4;
  const int q0 = qt * 64;

  // padded strides (72 / 136 elems) -> 2-way bank aliasing only (free, m136)
  __shared__ bf16_t ldsQ[64 * 72];        // 64 q rows x 64 d
  __shared__ bf16_t ldsK[128 * 72];       // 128 keys x 64 d
  __shared__ bf16_t ldsV[64 * 136];       // 64 d x 128 keys (from Vpt)
  __shared__ bf16_t ldsP[4][16 * 136];    // per-wave P tile: 16 q x 128 keys

  // ---- stage Q tile (once) ----
#pragma unroll
  for (int it = 0; it < 2; ++it) {
    int idx = tid + it * 256;            // 0..511
    int row = idx >> 3, c8 = idx & 7;    // 64 rows x 8 chunks of 8 bf16
    *(uint4*)&ldsQ[row * 72 + c8 * 8] =
        *(const uint4*)&Qp[(size_t)(b * S_LEN + q0 + row) * EMB + hq * HDIM + c8 * 8];
  }
  __syncthreads();

  // Q fragments: A[m=lane&15][k=quad*8+j]  (m120-verified A layout)
  bf16x8 qf[2];
#pragma unroll
  for (int ks = 0; ks < 2; ++ks)
    qf[ks] = *(const bf16x8*)&ldsQ[(wave * 16 + ll) * 72 + ks * 32 + quad * 8];

  float m_i[4], l_i[4];
#pragma unroll
  for (int r = 0; r < 4; ++r) { m_i[r] = -1e30f; l_i[r] = 0.f; }

  // ---- pass 1: online (m, l) ----
  for (int ch = 0; ch < 16; ++ch) {
    __syncthreads();
#pragma unroll
    for (int it = 0; it < 4; ++it) {
      int idx = tid + it * 256;          // 0..1023
      int row = idx >> 3, c8 = idx & 7;  // 128 keys x 8 chunks
      *(uint4*)&ldsK[row * 72 + c8 * 8] =
          *(const uint4*)&Kp[(size_t)(b * S_LEN + ch * 128 + row) * KVD + hkv * HDIM + c8 * 8];
    }
    __syncthreads();

    f32x4 s[8] = {};
#pragma unroll
    for (int nt = 0; nt < 8; ++nt)
#pragma unroll
      for (int ks = 0; ks < 2; ++ks) {
        bf16x8 kf = *(const bf16x8*)&ldsK[(nt * 16 + ll) * 72 + ks * 32 + quad * 8];
        s[nt] = MFMA16(qf[ks], kf, s[nt]);
      }

#pragma unroll
    for (int r = 0; r < 4; ++r) {
      float cmax = s[0][r];
#pragma unroll
      for (int nt = 1; nt < 8; ++nt) cmax = fmaxf(cmax, s[nt][r]);
#pragma unroll
      for (int off = 1; off < 16; off <<= 1)
        cmax = fmaxf(cmax, __shfl_xor(cmax, off, 16));
      float mnew = fmaxf(m_i[r], cmax);
      float csum = 0.f;
#pragma unroll
      for (int nt = 0; nt < 8; ++nt) csum += __expf(s[nt][r] - mnew);
#pragma unroll
      for (int off = 1; off < 16; off <<= 1)
        csum += __shfl_xor(csum, off, 16);
      l_i[r] = l_i[r] * __expf(m_i[r] - mnew) + csum;
      m_i[r] = mnew;
    }
  }

  float inv_l[4];
#pragma unroll
  for (int r = 0; r < 4; ++r) inv_l[r] = 1.0f / l_i[r];

  // ---- pass 2: recompute, write P, accumulate O = P @ V ----
  f32x4 o[4] = {};
  float* ab = attn + (size_t)((b * NQH + hq) * S_LEN + q0 + wave * 16 + quad * 4) * S_LEN + ll;

  for (int ch = 0; ch < 16; ++ch) {
    __syncthreads();
#pragma unroll
    for (int it = 0; it < 4; ++it) {
      int idx = tid + it * 256;
      int row = idx >> 3, c8 = idx & 7;
      *(uint4*)&ldsK[row * 72 + c8 * 8] =
          *(const uint4*)&Kp[(size_t)(b * S_LEN + ch * 128 + row) * KVD + hkv * HDIM + c8 * 8];
    }
#pragma unroll
    for (int it = 0; it < 4; ++it) {
      int idx = tid + it * 256;
      int row = idx >> 4, c8 = idx & 15;  // 64 d-rows x 16 chunks of 8
      *(uint4*)&ldsV[row * 136 + c8 * 8] =
          *(const uint4*)&Vpt[((size_t)(b * NKVH + hkv) * HDIM + row) * S_LEN + ch * 128 + c8 * 8];
    }
    __syncthreads();

    f32x4 s[8] = {};
#pragma unroll
    for (int nt = 0; nt < 8; ++nt)
#pragma unroll
      for (int ks = 0; ks < 2; ++ks) {
        bf16x8 kf = *(const bf16x8*)&ldsK[(nt * 16 + ll) * 72 + ks * 32 + quad * 8];
        s[nt] = MFMA16(qf[ks], kf, s[nt]);
      }

#pragma unroll
    for (int nt = 0; nt < 8; ++nt)
#pragma unroll
      for (int r = 0; r < 4; ++r) {
        float p = __expf(s[nt][r] - m_i[r]) * inv_l[r];
        ab[(size_t)r * S_LEN + ch * 128 + nt * 16] = p;
        ldsP[wave][(quad * 4 + r) * 136 + nt * 16 + ll] = (bf16_t)p;
      }
    __threadfence_block();  // order per-wave LDS P writes before A-frag reads

#pragma unroll
    for (int kk = 0; kk < 4; ++kk) {
      bf16x8 pf = *(const bf16x8*)&ldsP[wave][ll * 136 + kk * 32 + quad * 8];
#pragma unroll
      for (int nt2 = 0; nt2 < 4; ++nt2) {
        bf16x8 vf = *(const bf16x8*)&ldsV[(nt2 * 16 + ll) * 136 + kk * 32 + quad * 8];
        o[nt2] = MFMA16(pf, vf, o[nt2]);
      }
    }
  }

  // ---- write O (bf16), layout (b, s, hq*64+d) ----
#pragma unroll
  for (int nt2 = 0; nt2 < 4; ++nt2)
#pragma unroll
    for (int r = 0; r < 4; ++r) {
      int q = q0 + wave * 16 + quad * 4 + r;
      Ob[(size_t)(b * S_LEN + q) * EMB + hq * HDIM + nt2 * 16 + ll] = (bf16_t)o[nt2][r];
    }
}

// ---------------- launch ----------------
extern "C" void kernel_launch(void* const* d_in, const int* in_sizes, int n_in,
                              void* d_out, int out_size, void* d_ws, size_t ws_size,
                              hipStream_t stream) {
  const float* query = (const float*)d_in[0];
  const float* key   = (const float*)d_in[1];
  const float* value = (const float*)d_in[2];
  const float* Wq = (const float*)d_in[3];
  const float* bq = (const float*)d_in[4];
  const float* Wk = (const float*)d_in[5];
  const float* bk = (const float*)d_in[6];
  const float* Wv = (const float*)d_in[7];
  const float* bv = (const float*)d_in[8];
  const float* Wo = (const float*)d_in[9];
  const float* bo = (const float*)d_in[10];

  float* out  = (float*)d_out;                      // (B,S,E)
  float* attn = out + (size_t)BATCH * S_LEN * EMB;  // (B,32,S,S)

  const size_t M = (size_t)BATCH * S_LEN;  // 4096 tokens
  char* ws = (char*)d_ws;
  bf16_t* Qb  = (bf16_t*)ws; ws += M * EMB * 2;
  bf16_t* Kb  = (bf16_t*)ws; ws += M * EMB * 2;
  bf16_t* Vb  = (bf16_t*)ws; ws += M * EMB * 2;
  bf16_t* WqT = (bf16_t*)ws; ws += (size_t)EMB * EMB * 2;
  bf16_t* WkT = (bf16_t*)ws; ws += (size_t)KVD * EMB * 2;
  bf16_t* WvT = (bf16_t*)ws; ws += (size_t)KVD * EMB * 2;
  bf16_t* WoT = (bf16_t*)ws; ws += (size_t)EMB * EMB * 2;
  bf16_t* Qp  = (bf16_t*)ws; ws += M * EMB * 2;
  bf16_t* Kp  = (bf16_t*)ws; ws += M * KVD * 2;
  bf16_t* Vp  = (bf16_t*)ws; ws += M * KVD * 2;
  bf16_t* Vpt = (bf16_t*)ws; ws += M * KVD * 2;
  bf16_t* Ob  = (bf16_t*)ws; ws += M * EMB * 2;

  const int n_tok = (int)(M * EMB);  // 8388608
  cvt_f32_bf16<<<n_tok / 1024, 256, 0, stream>>>(query, Qb, n_tok);
  cvt_f32_bf16<<<n_tok / 1024, 256, 0, stream>>>(key,   Kb, n_tok);
  cvt_f32_bf16<<<n_tok / 1024, 256, 0, stream>>>(value, Vb, n_tok);

  transpose_f32_bf16<<<dim3(EMB / 32, EMB / 32), dim3(32, 8), 0, stream>>>(Wq, WqT, EMB, EMB);
  transpose_f32_bf16<<<dim3(KVD / 32, EMB / 32), dim3(32, 8), 0, stream>>>(Wk, WkT, EMB, KVD);
  transpose_f32_bf16<<<dim3(KVD / 32, EMB / 32), dim3(32, 8), 0, stream>>>(Wv, WvT, EMB, KVD);
  transpose_f32_bf16<<<dim3(EMB / 32, EMB / 32), dim3(32, 8), 0, stream>>>(Wo, WoT, EMB, EMB);

  // softmax scale folded into Q projection
  gemm_bt<bf16_t><<<dim3(EMB / 128, M / 128), 256, 0, stream>>>(Qb, WqT, bq, Qp,
                                                                (int)M, EMB, EMB, 0.125f);
  gemm_bt<bf16_t><<<dim3(KVD / 128, M / 128), 256, 0, stream>>>(Kb, WkT, bk, Kp,
                                                                (int)M, KVD, EMB, 1.0f);
  gemm_bt<bf16_t><<<dim3(KVD / 128, M / 128), 256, 0, stream>>>(Vb, WvT, bv, Vp,
                                                                (int)M, KVD, EMB, 1.0f);

  // V: (b, s, kvd) -> (b, kvd, s)  == (B, NKVH, HDIM, S)
  transpose_bf16<<<dim3(KVD / 32, S_LEN / 32, BATCH), dim3(32, 8), 0, stream>>>(Vp, Vpt, S_LEN, KVD);

  attn_kernel<<<dim3(S_LEN / 64, NQH, BATCH), 256, 0, stream>>>(Qp, Kp, Vpt, attn, Ob);

  gemm_bt<float><<<dim3(EMB / 128, M / 128), 256, 0, stream>>>(Ob, WoT, bo, out,
                                                               (int)M, EMB, EMB, 1.0f);
}